// Round 6
// baseline (491.511 us; speedup 1.0000x reference)
//
#include <hip/hip_runtime.h>
#include <hip/hip_bf16.h>
#include <hip/hip_fp16.h>

#define NN 20000
#define NE 100000
#define NGR 64

using bf16 = __hip_bfloat16;
typedef __attribute__((ext_vector_type(8))) short v8s;
typedef __attribute__((ext_vector_type(4))) float v4f;
typedef _Float16 h2f __attribute__((ext_vector_type(2)));

__device__ __forceinline__ float ldf(const void* p, int idx, int isbf) {
  if (isbf) return __bfloat162float(((const bf16*)p)[idx]);
  return ((const float*)p)[idx];
}
__device__ __forceinline__ unsigned short f2bfbits(float v) {
  unsigned int b = __float_as_uint(v);
  b += 0x7fffu + ((b >> 16) & 1u);
  return (unsigned short)(b >> 16);
}

// pack two f32 -> one dword of two f16 (lo = a, hi = b)
__device__ __forceinline__ unsigned int pkh2(float a, float b) {
#if __has_builtin(__builtin_amdgcn_cvt_pkrtz)
  auto r = __builtin_amdgcn_cvt_pkrtz(a, b);  // __fp16 ext_vector(2)
  return __builtin_bit_cast(unsigned int, r);
#else
  unsigned int lo = __half_as_ushort(__float2half(a));
  unsigned int hi = __half_as_ushort(__float2half(b));
  return lo | (hi << 16);
#endif
}
// c += dot2(z, q) with z,q packed f16 pairs
__device__ __forceinline__ float dot2a(unsigned int z, unsigned int q, float c) {
#if __has_builtin(__builtin_amdgcn_fdot2)
  return __builtin_amdgcn_fdot2(__builtin_bit_cast(h2f, z),
                                __builtin_bit_cast(h2f, q), c, false);
#else
  h2f zh = __builtin_bit_cast(h2f, z), qh = __builtin_bit_cast(h2f, q);
  return c + (float)zh.x * (float)qh.x + (float)zh.y * (float)qh.y;
#endif
}

// ---------------- dtype detector: 1 wave, writes flag (1=bf16, 0=f32) ----
__global__ __launch_bounds__(64) void k_detect(const unsigned short* __restrict__ xr,
                                               int* __restrict__ flag) {
  const int t = threadIdx.x;
  int cnt = 0;
#pragma unroll
  for (int j = 0; j < 4; j++) {
    unsigned short w = xr[t * 4 + j];
    int ex = (w >> 7) & 0xFF;
    cnt += (ex >= 118 && ex <= 131) ? 1 : 0;
  }
#pragma unroll
  for (int m = 32; m >= 1; m >>= 1) cnt += __shfl_xor(cnt, m, 64);
  if (t == 0) *flag = (cnt >= 192) ? 1 : 0;
}

// ---------------- degree histogram ----------------
__global__ __launch_bounds__(256) void k_deg(const int* __restrict__ ei,
                                             int* __restrict__ deg_src,
                                             int* __restrict__ deg_in) {
  int e = blockIdx.x * 256 + threadIdx.x;
  if (e < NE) {
    atomicAdd(&deg_src[ei[e]], 1);
    atomicAdd(&deg_in[ei[NE + e]], 1);
  }
}

// ---------------- single-block exclusive scan, 256 threads x 80 ----------
__global__ __launch_bounds__(256) void k_scan(const int* __restrict__ deg,
                                              int* __restrict__ off,
                                              int* __restrict__ cur) {
  constexpr int T = 256, CH = 80;  // 256*80 = 20480 >= NN
  __shared__ int sums[T];
  const int t = threadIdx.x;
  const int base = t * CH;
  int s = 0;
  for (int j = 0; j < CH; j++) {
    int i = base + j;
    s += (i < NN) ? deg[i] : 0;
  }
  sums[t] = s;
  __syncthreads();
  for (int st = 1; st < T; st <<= 1) {
    int v = (t >= st) ? sums[t - st] : 0;
    __syncthreads();
    sums[t] += v;
    __syncthreads();
  }
  int run = sums[t] - s;
  for (int j = 0; j < CH; j++) {
    int i = base + j;
    if (i < NN) {
      int v = deg[i];
      off[i] = run;
      cur[i] = run;
      run += v;
    }
  }
  if (t == T - 1) off[NN] = sums[T - 1];
}

// ---------------- CSR scatter ----------------
__global__ __launch_bounds__(256) void k_scatter(const int* __restrict__ ei,
                                                 int* __restrict__ cur,
                                                 int* __restrict__ ebs) {
  int e = blockIdx.x * 256 + threadIdx.x;
  if (e < NE) {
    int p = atomicAdd(&cur[ei[e]], 1);
    if (p >= 0 && p < NE) ebs[p] = e;
  }
}

// ---------------- W2 -> MFMA B-fragment pre-shuffle (IN must be 64) -------
// W2s[F*512 + lane*8 + j] = W2[k2][i*64 + o2],
//   F=(k2*4+ot)*2+ks, i=ks*32+(lane>>4)*8+j, o2=ot*16+(lane&15)
template <int KH, int IN>
__global__ __launch_bounds__(256) void k_shuffle(const void* __restrict__ W2,
                                                 unsigned short* __restrict__ W2s,
                                                 const int* __restrict__ flag) {
  const int f = *flag;
  int t = blockIdx.x * 256 + threadIdx.x;  // KH*8*64 threads total
  int lane = t & 63, F = t >> 6;
  int ks = F & 1, ot = (F >> 1) & 3, k2 = F >> 3;
  int quad = lane >> 4, col = lane & 15;
  unsigned short tmp[8];
#pragma unroll
  for (int j = 0; j < 8; j++) {
    int i = ks * 32 + quad * 8 + j;
    tmp[j] = f2bfbits(ldf(W2, k2 * (IN * 64) + i * 64 + ot * 16 + col, f));
  }
  *(uint4*)(W2s + (size_t)F * 512 + lane * 8) = *(uint4*)tmp;
}

// ---------------- fused node-first NNConv message pass ----------------
// CHUNK-SPLIT across grid.y (R5: serial 8-chunk loop w/ 2 barriers each was
// latency-bound at 25% VALUBusy, 35% occupancy). Each block handles ONE
// K-chunk of its node group; partial messages accumulate via agg atomics.
// r2 (the eb2 term) added by chunk-0 blocks only.
// msg[e][o] += sum_{k in chunk} z[e][k]*Q[src[e]][k][o]  (+ r2[src[e]][o])
template <int IN, int KH, int HMODE, int QMFMA>
__global__ __launch_bounds__(512, 4) void k_fused2(
    const void* __restrict__ h_in, const void* __restrict__ eW1,
    const void* __restrict__ eb1, const void* __restrict__ W2,
    const unsigned short* __restrict__ W2s, const void* __restrict__ eb2,
    const void* __restrict__ ea, const int* __restrict__ ei,
    const int* __restrict__ src_off, const int* __restrict__ ebs,
    float* __restrict__ agg, const int* __restrict__ flag) {
  constexpr int NPG = 16, KC = 16, EB = 128;
  constexpr int QNS = (KC / 2) * 64 + 1;  // 513: rows stride 1 mod 32 banks
  constexpr int ZROW = 8;                 // 8 pair-dwords per edge

  __shared__ float hA[NPG][IN];
  __shared__ float r2[NPG][64];
  __shared__ __align__(16) unsigned int Qc[NPG * QNS];
  __shared__ float eW1S[4][KC];
  __shared__ float ebS[KC];
  __shared__ float eaS[EB][4];
  __shared__ __align__(16) unsigned int zB[EB * ZROW];
  __shared__ int esrcS[EB], edstS[EB];
  __shared__ __align__(16) unsigned short hF[QMFMA ? 2 : 1][64][8];

  const int f = *flag;
  const int tid = threadIdx.x;
  const int o = tid & 63;
  const int kq = tid >> 6;     // wave id 0..7
  const int c = blockIdx.y;    // K-chunk id 0..KH/KC-1
  const int n0 = blockIdx.x * NPG;

  // ---- stage h rows, eW1/eb1 chunk slice ----
  for (int idx = tid; idx < NPG * IN; idx += 512) {
    int n = idx / IN, i = idx - n * IN;
    hA[n][i] = (HMODE == 1) ? ((const float*)h_in)[(n0 + n) * IN + i]
                            : ldf(h_in, (n0 + n) * IN + i, f);
  }
  if (tid < 4 * KC) {
    int i = tid / KC, kk = tid - i * KC;
    eW1S[i][kk] = ldf(eW1, i * KH + c * KC + kk, f);
  }
  if (tid < KC) ebS[tid] = ldf(eb1, c * KC + tid, f);
  __syncthreads();

  if (c == 0) {  // r2[n][o]: wave kq owns nodes kq*2, kq*2+1
    const int nb = kq * 2;
    float a0 = 0.f, a1 = 0.f;
    for (int i = 0; i < IN; i++) {
      float wv = ldf(eb2, i * 64 + o, f);
      a0 += hA[nb + 0][i] * wv;
      a1 += hA[nb + 1][i] * wv;
    }
    r2[nb + 0][o] = a0;
    r2[nb + 1][o] = a1;
  }
  if constexpr (QMFMA) {  // A-fragment staging (lane l: m=l&15, k=ks*32+quad*8+j)
    if (tid < 128) {
      int l = tid & 63, ks = tid >> 6;
#pragma unroll
      for (int j = 0; j < 8; j++)
        hF[ks][l][j] = f2bfbits(hA[l & 15][ks * 32 + (l >> 4) * 8 + j]);
    }
  }
  __syncthreads();  // hF / r2 visible

  // ---- compute this chunk's Q into regs, write Qc (f16 pairs) ----
  if constexpr (QMFMA) {
    v8s aF0 = *(const v8s*)&hF[0][o][0];
    v8s aF1 = *(const v8s*)&hF[1][o][0];
    v4f acc8[8];
#pragma unroll
    for (int nt = 0; nt < 8; nt++) {
      acc8[nt] = (v4f){0.f, 0.f, 0.f, 0.f};
      const int k2 = c * KC + kq * 2 + (nt >> 2);
      const int Fb = (k2 * 4 + (nt & 3)) * 2;
      v8s b0 = *(const v8s*)(W2s + (size_t)Fb * 512 + o * 8);
      v8s b1 = *(const v8s*)(W2s + (size_t)(Fb + 1) * 512 + o * 8);
      acc8[nt] =
          __builtin_amdgcn_mfma_f32_16x16x32_bf16(aF0, b0, acc8[nt], 0, 0, 0);
      acc8[nt] =
          __builtin_amdgcn_mfma_f32_16x16x32_bf16(aF1, b1, acc8[nt], 0, 0, 0);
    }
    const int quad = o >> 4;
#pragma unroll
    for (int nt = 0; nt < 4; nt++) {
      const int o2 = nt * 16 + (o & 15);
#pragma unroll
      for (int r = 0; r < 4; r++)
        Qc[(quad * 4 + r) * QNS + kq * 64 + o2] =
            pkh2(acc8[nt][r], acc8[nt + 4][r]);
    }
  } else {
    const int kg0 = c * KC + kq * 2;
    const int w2base = kg0 * (IN * 64) + o;
    float w0[IN], w1[IN];
#pragma unroll
    for (int j = 0; j < IN; j++) {
      w0[j] = ldf(W2, w2base + j * 64, f);
      w1[j] = ldf(W2, w2base + IN * 64 + j * 64, f);
    }
#pragma unroll
    for (int n = 0; n < NPG; n++) {
      float a0 = 0.f, a1 = 0.f;
#pragma unroll
      for (int j = 0; j < IN; j++) {
        float hv = hA[n][j];
        a0 += hv * w0[j];
        a1 += hv * w1[j];
      }
      Qc[n * QNS + kq * 64 + o] = pkh2(a0, a1);
    }
  }
  // Qc visibility folded into the batch loop's first barrier.

  const int estart = src_off[n0];
  const int ecount = src_off[n0 + NPG] - estart;

  for (int b = 0; b < ecount; b += EB) {
    const int bc = min(EB, ecount - b);
    __syncthreads();  // b==0: Qc visible; b>0: prev readers done w/ meta/zB
    if (tid < bc) {
      int eid = ebs[estart + b + tid];
      esrcS[tid] = ei[eid] - n0;
      edstS[tid] = ei[NE + eid];
#pragma unroll
      for (int i = 0; i < 4; i++) eaS[tid][i] = ldf(ea, eid * 4 + i, f);
    }
    __syncthreads();  // meta/eaS visible

    // z for this chunk: thread -> (edge = tid&127, 4 k's per quarter)
    const int ze = tid & 127, kseg = tid >> 7;  // kseg 0..3
    if (ze < bc) {
      float zv[4];
#pragma unroll
      for (int jj = 0; jj < 4; jj++) {
        int kk = kseg * 4 + jj;
        float a = ebS[kk];
#pragma unroll
        for (int i = 0; i < 4; i++) a += eaS[ze][i] * eW1S[i][kk];
        zv[jj] = fmaxf(a, 0.f);
      }
      uint2 p;
      p.x = pkh2(zv[0], zv[1]);
      p.y = pkh2(zv[2], zv[3]);
      *(uint2*)&zB[ze * ZROW + kseg * 2] = p;
    }
    __syncthreads();  // zB visible

    // ---- message accumulate via dot2 (contiguous edges, src-cached Q) ----
    const int lo = (bc * kq) >> 3, hi = (bc * (kq + 1)) >> 3;
    unsigned int q0 = 0, q1 = 0, q2 = 0, q3 = 0, q4 = 0, q5 = 0, q6 = 0,
                 q7 = 0;
    int sprev = -1;
#pragma unroll
    for (int j = 0; j < EB / 8; j++) {
      const int e = lo + j;
      if (e < hi) {
        const int s = esrcS[e];  // wave-uniform
        if (s != sprev) {
          const unsigned int* qp = &Qc[s * QNS + o];
          q0 = qp[0 * 64]; q1 = qp[1 * 64]; q2 = qp[2 * 64]; q3 = qp[3 * 64];
          q4 = qp[4 * 64]; q5 = qp[5 * 64]; q6 = qp[6 * 64]; q7 = qp[7 * 64];
          sprev = s;
        }
        const uint2 za = *(const uint2*)&zB[e * ZROW + 0];
        const uint2 zb = *(const uint2*)&zB[e * ZROW + 2];
        const uint2 zc = *(const uint2*)&zB[e * ZROW + 4];
        const uint2 zd = *(const uint2*)&zB[e * ZROW + 6];
        float m = 0.f;
        m = dot2a(za.x, q0, m);
        m = dot2a(za.y, q1, m);
        m = dot2a(zb.x, q2, m);
        m = dot2a(zb.y, q3, m);
        m = dot2a(zc.x, q4, m);
        m = dot2a(zc.y, q5, m);
        m = dot2a(zd.x, q6, m);
        m = dot2a(zd.y, q7, m);
        if (c == 0) m += r2[s][o];
        atomicAdd(&agg[(size_t)edstS[e] * 64 + o], m);
      }
    }
  }  // batches
}

// ---------------- wave-wide sum over 64 lanes ----------------
__device__ __forceinline__ float wave_sum(float v) {
#pragma unroll
  for (int m = 32; m >= 1; m >>= 1) v += __shfl_xor(v, m, 64);
  return v;
}

// ---------------- node update 1: h1 = LN(relu(agg/deg + x@root1 + bias1)) -
// 8 nodes per wave; root1 column hoisted to regs (R4: per-node tiny blocks
// were latency-bound at 4.4% VALUBusy).
__global__ __launch_bounds__(256, 4) void k_node1(
    const float* __restrict__ agg1, const int* __restrict__ deg_in,
    const void* __restrict__ x, const void* __restrict__ root1,
    const void* __restrict__ bias1, const void* __restrict__ g1,
    const void* __restrict__ b1, float* __restrict__ h1,
    const int* __restrict__ flag) {
  constexpr int NPW = 8;
  const int f = *flag;
  const int tid = threadIdx.x;
  const int o = tid & 63;
  const int w = tid >> 6;
  float r1c[4];
#pragma unroll
  for (int i = 0; i < 4; i++) r1c[i] = ldf(root1, i * 64 + o, f);
  const float bs = ldf(bias1, o, f);
  const float gv = ldf(g1, o, f);
  const float bv = ldf(b1, o, f);
  const int wid = blockIdx.x * 4 + w;
  const int nbeg = wid * NPW;
  const int nend = min(nbeg + NPW, NN);
  for (int n = nbeg; n < nend; n++) {
    float v = agg1[(size_t)n * 64 + o] / fmaxf((float)deg_in[n], 1.f) + bs;
#pragma unroll
    for (int i = 0; i < 4; i++) v += ldf(x, n * 4 + i, f) * r1c[i];
    v = fmaxf(v, 0.f);
    const float mu = wave_sum(v) * (1.f / 64.f);
    const float d = v - mu;
    const float var = wave_sum(d * d) * (1.f / 64.f);
    h1[(size_t)n * 64 + o] = d * rsqrtf(var + 1e-5f) * gv + bv;
  }
}

// ---------------- node update 2 + pooled accumulation ----------------
// 8 nodes per wave; root2 COLUMN in 64 VGPRs; h1 row via LDS broadcast;
// sorted-batch segment flush cuts psum atomics 1.28M -> ~180K.
__global__ __launch_bounds__(256, 4) void k_node2(
    const float* __restrict__ agg2, const int* __restrict__ deg_in,
    const float* __restrict__ h1, const void* __restrict__ root2,
    const void* __restrict__ bias2, const void* __restrict__ g2,
    const void* __restrict__ b2, const int* __restrict__ batch,
    float* __restrict__ psum, float* __restrict__ pcnt,
    const int* __restrict__ flag) {
  constexpr int NPW = 8;
  __shared__ float hS[4][64];
  const int f = *flag;
  const int tid = threadIdx.x;
  const int o = tid & 63;
  const int w = tid >> 6;
  float r2c[64];
#pragma unroll
  for (int i = 0; i < 64; i++) r2c[i] = ldf(root2, i * 64 + o, f);
  const float bs = ldf(bias2, o, f);
  const float gv = ldf(g2, o, f);
  const float bv = ldf(b2, o, f);
  const int wid = blockIdx.x * 4 + w;
  const int nbeg = wid * NPW;
  const int nend = min(nbeg + NPW, NN);
  float acc = 0.f;
  int curbi = -1, cnt = 0;
  for (int n = nbeg; n < nend; n++) {
    hS[w][o] = h1[(size_t)n * 64 + o];
    float v = agg2[(size_t)n * 64 + o] / fmaxf((float)deg_in[n], 1.f) + bs;
#pragma unroll
    for (int i = 0; i < 64; i++) v += hS[w][i] * r2c[i];
    v = fmaxf(v, 0.f);
    const float mu = wave_sum(v) * (1.f / 64.f);
    const float d = v - mu;
    const float var = wave_sum(d * d) * (1.f / 64.f);
    const float out = d * rsqrtf(var + 1e-5f) * gv + bv;
    const int bi = batch[n];
    if (bi != curbi) {
      if (curbi >= 0) {
        atomicAdd(&psum[curbi * 64 + o], acc);
        if (o == 0) atomicAdd(&pcnt[curbi], (float)cnt);
      }
      acc = 0.f;
      cnt = 0;
      curbi = bi;
    }
    acc += out;
    cnt++;
  }
  if (curbi >= 0) {
    atomicAdd(&psum[curbi * 64 + o], acc);
    if (o == 0) atomicAdd(&pcnt[curbi], (float)cnt);
  }
}

// ---------------- final mean + dtype-flagged output ----------------
__global__ __launch_bounds__(256) void k_out(const float* __restrict__ psum,
                                             const float* __restrict__ pcnt,
                                             void* __restrict__ out,
                                             const int* __restrict__ flag) {
  const int idx = blockIdx.x * 256 + threadIdx.x;  // 4096 total
  float v = psum[idx] / fmaxf(pcnt[idx >> 6], 1.f);
  if (*flag)
    ((bf16*)out)[idx] = __float2bfloat16(v);
  else
    ((float*)out)[idx] = v;
}

extern "C" void kernel_launch(void* const* d_in, const int* in_sizes, int n_in,
                              void* d_out, int out_size, void* d_ws,
                              size_t ws_size, hipStream_t stream) {
  (void)in_sizes; (void)n_in; (void)out_size; (void)ws_size;
  const void* x = d_in[0];
  const int* ei = (const int*)d_in[1];
  const void* ea = d_in[2];
  const int* batch = (const int*)d_in[3];
  const void* eW1_1 = d_in[4];
  const void* eb1_1 = d_in[5];
  const void* eW2_1 = d_in[6];
  const void* eb2_1 = d_in[7];
  const void* root1 = d_in[8];
  const void* bias1 = d_in[9];
  const void* g1 = d_in[10];
  const void* b1 = d_in[11];
  const void* eW1_2 = d_in[12];
  const void* eb1_2 = d_in[13];
  const void* eW2_2 = d_in[14];
  const void* eb2_2 = d_in[15];
  const void* root2 = d_in[16];
  const void* bias2 = d_in[17];
  const void* g2 = d_in[18];
  const void* b2 = d_in[19];

  char* w = (char*)d_ws;
  size_t off = 0;
  auto alloc = [&](size_t bytes) -> void* {
    void* p = w + off;
    off = (off + bytes + 255) & ~(size_t)255;
    return p;
  };
  float* agg1 = (float*)alloc((size_t)NN * 64 * 4);
  float* agg2 = (float*)alloc((size_t)NN * 64 * 4);
  float* psum = (float*)alloc((size_t)NGR * 64 * 4);
  float* pcnt = (float*)alloc((size_t)NGR * 4);
  int* deg_src = (int*)alloc((size_t)NN * 4);
  int* deg_in = (int*)alloc((size_t)NN * 4);
  const size_t zero_bytes = off;  // everything above must start at 0
  int* src_off = (int*)alloc((size_t)(NN + 1) * 4);
  int* cur = (int*)alloc((size_t)NN * 4);
  int* ebs = (int*)alloc((size_t)NE * 4);
  int* flag = (int*)alloc(256);
  float* h1 = (float*)alloc((size_t)NN * 64 * 4);
  unsigned short* W2s = (unsigned short*)alloc((size_t)128 * 8 * 64 * 8 * 2);

  hipMemsetAsync(d_ws, 0, zero_bytes, stream);

  k_detect<<<1, 64, 0, stream>>>((const unsigned short*)x, flag);
  k_deg<<<(NE + 255) / 256, 256, 0, stream>>>(ei, deg_src, deg_in);
  k_scan<<<1, 256, 0, stream>>>(deg_src, src_off, cur);
  k_scatter<<<(NE + 255) / 256, 256, 0, stream>>>(ei, cur, ebs);
  k_shuffle<128, 64><<<256, 256, 0, stream>>>(eW2_2, W2s, flag);
  k_fused2<4, 64, 0, 0><<<dim3(NN / 16, 64 / 16), 512, 0, stream>>>(
      x, eW1_1, eb1_1, eW2_1, W2s, eb2_1, ea, ei, src_off, ebs, agg1, flag);
  k_node1<<<(NN + 8 * 4 - 1) / (8 * 4), 256, 0, stream>>>(
      agg1, deg_in, x, root1, bias1, g1, b1, h1, flag);
  k_fused2<64, 128, 1, 1><<<dim3(NN / 16, 128 / 16), 512, 0, stream>>>(
      h1, eW1_2, eb1_2, eW2_2, W2s, eb2_2, ea, ei, src_off, ebs, agg2, flag);
  k_node2<<<(NN + 8 * 4 - 1) / (8 * 4), 256, 0, stream>>>(
      agg2, deg_in, h1, root2, bias2, g2, b2, batch, psum, pcnt, flag);
  k_out<<<(NGR * 64) / 256, 256, 0, stream>>>(psum, pcnt, d_out, flag);
}

// Round 8
// 410.104 us; speedup vs baseline: 1.1985x; 1.1985x over previous
//
#include <hip/hip_runtime.h>
#include <hip/hip_bf16.h>
#include <hip/hip_fp16.h>

#define NN 20000
#define NE 100000
#define NGR 64

using bf16 = __hip_bfloat16;
typedef __attribute__((ext_vector_type(8))) short v8s;
typedef __attribute__((ext_vector_type(4))) float v4f;
typedef _Float16 h2f __attribute__((ext_vector_type(2)));

__device__ __forceinline__ float ldf(const void* p, int idx, int isbf) {
  if (isbf) return __bfloat162float(((const bf16*)p)[idx]);
  return ((const float*)p)[idx];
}
__device__ __forceinline__ unsigned short f2bfbits(float v) {
  unsigned int b = __float_as_uint(v);
  b += 0x7fffu + ((b >> 16) & 1u);
  return (unsigned short)(b >> 16);
}

// pack two f32 -> one dword of two f16 (lo = a, hi = b)
__device__ __forceinline__ unsigned int pkh2(float a, float b) {
#if __has_builtin(__builtin_amdgcn_cvt_pkrtz)
  auto r = __builtin_amdgcn_cvt_pkrtz(a, b);  // __fp16 ext_vector(2)
  return __builtin_bit_cast(unsigned int, r);
#else
  unsigned int lo = __half_as_ushort(__float2half(a));
  unsigned int hi = __half_as_ushort(__float2half(b));
  return lo | (hi << 16);
#endif
}
// c += dot2(z, q) with z,q packed f16 pairs
__device__ __forceinline__ float dot2a(unsigned int z, unsigned int q, float c) {
#if __has_builtin(__builtin_amdgcn_fdot2)
  return __builtin_amdgcn_fdot2(__builtin_bit_cast(h2f, z),
                                __builtin_bit_cast(h2f, q), c, false);
#else
  h2f zh = __builtin_bit_cast(h2f, z), qh = __builtin_bit_cast(h2f, q);
  return c + (float)zh.x * (float)qh.x + (float)zh.y * (float)qh.y;
#endif
}

// ---------------- dtype detector: 1 wave, writes flag (1=bf16, 0=f32) ----
__global__ __launch_bounds__(64) void k_detect(const unsigned short* __restrict__ xr,
                                               int* __restrict__ flag) {
  const int t = threadIdx.x;
  int cnt = 0;
#pragma unroll
  for (int j = 0; j < 4; j++) {
    unsigned short w = xr[t * 4 + j];
    int ex = (w >> 7) & 0xFF;
    cnt += (ex >= 118 && ex <= 131) ? 1 : 0;
  }
#pragma unroll
  for (int m = 32; m >= 1; m >>= 1) cnt += __shfl_xor(cnt, m, 64);
  if (t == 0) *flag = (cnt >= 192) ? 1 : 0;
}

// ---------------- degree histogram ----------------
__global__ __launch_bounds__(256) void k_deg(const int* __restrict__ ei,
                                             int* __restrict__ deg_src,
                                             int* __restrict__ deg_in) {
  int e = blockIdx.x * 256 + threadIdx.x;
  if (e < NE) {
    atomicAdd(&deg_src[ei[e]], 1);
    atomicAdd(&deg_in[ei[NE + e]], 1);
  }
}

// ---------------- single-block exclusive scan, 256 threads x 80 ----------
__global__ __launch_bounds__(256) void k_scan(const int* __restrict__ deg,
                                              int* __restrict__ off,
                                              int* __restrict__ cur) {
  constexpr int T = 256, CH = 80;  // 256*80 = 20480 >= NN
  __shared__ int sums[T];
  const int t = threadIdx.x;
  const int base = t * CH;
  int s = 0;
  for (int j = 0; j < CH; j++) {
    int i = base + j;
    s += (i < NN) ? deg[i] : 0;
  }
  sums[t] = s;
  __syncthreads();
  for (int st = 1; st < T; st <<= 1) {
    int v = (t >= st) ? sums[t - st] : 0;
    __syncthreads();
    sums[t] += v;
    __syncthreads();
  }
  int run = sums[t] - s;
  for (int j = 0; j < CH; j++) {
    int i = base + j;
    if (i < NN) {
      int v = deg[i];
      off[i] = run;
      cur[i] = run;
      run += v;
    }
  }
  if (t == T - 1) off[NN] = sums[T - 1];
}

// ---------------- CSR scatter ----------------
__global__ __launch_bounds__(256) void k_scatter(const int* __restrict__ ei,
                                                 int* __restrict__ cur,
                                                 int* __restrict__ ebs) {
  int e = blockIdx.x * 256 + threadIdx.x;
  if (e < NE) {
    int p = atomicAdd(&cur[ei[e]], 1);
    if (p >= 0 && p < NE) ebs[p] = e;
  }
}

// ---------------- W2 -> MFMA B-fragment pre-shuffle (IN must be 64) -------
// W2s[F*512 + lane*8 + j] = W2[k2][i*64 + o2],
//   F=(k2*4+ot)*2+ks, i=ks*32+(lane>>4)*8+j, o2=ot*16+(lane&15)
template <int KH, int IN>
__global__ __launch_bounds__(256) void k_shuffle(const void* __restrict__ W2,
                                                 unsigned short* __restrict__ W2s,
                                                 const int* __restrict__ flag) {
  const int f = *flag;
  int t = blockIdx.x * 256 + threadIdx.x;  // KH*8*64 threads total
  int lane = t & 63, F = t >> 6;
  int ks = F & 1, ot = (F >> 1) & 3, k2 = F >> 3;
  int quad = lane >> 4, col = lane & 15;
  unsigned short tmp[8];
#pragma unroll
  for (int j = 0; j < 8; j++) {
    int i = ks * 32 + quad * 8 + j;
    tmp[j] = f2bfbits(ldf(W2, k2 * (IN * 64) + i * 64 + ot * 16 + col, f));
  }
  *(uint4*)(W2s + (size_t)F * 512 + lane * 8) = *(uint4*)tmp;
}

// ---------------- fused node-first NNConv message pass (8 waves) ----------
// R5 structure (serial chunks, msg in regs — R6's grid chunk-split cost 8x
// atomic traffic, reverted). r2 stored f16 to cut LDS 54.3->50.8 KB ->
// 3 blocks/CU (was the 2-block LDS cliff). QNS=516 / ZROW=10 paddings are
// load-bearing (R6: 513/8 caused 4.57M bank-conflict cycles).
template <int IN, int KH, int HMODE, int QMFMA>
__global__ __launch_bounds__(512, 4) void k_fused2(
    const void* __restrict__ h_in, const void* __restrict__ eW1,
    const void* __restrict__ eb1, const void* __restrict__ W2,
    const unsigned short* __restrict__ W2s, const void* __restrict__ eb2,
    const void* __restrict__ ea, const int* __restrict__ ei,
    const int* __restrict__ src_off, const int* __restrict__ ebs,
    float* __restrict__ agg, const int* __restrict__ flag) {
  constexpr int NPG = 16, KC = 16, NCH = KH / KC, EB = 128;
  constexpr int QNS = (KC / 2) * 64 + 4;  // 516: quad stride 16 mod 32 (2-way)
  constexpr int ZROW = 10;                // stride 10 mod 32: conflict-free

  __shared__ float hA[NPG][IN];
  __shared__ _Float16 r2h[NPG][64];
  __shared__ __align__(16) unsigned int Qc[NPG * QNS];
  __shared__ float eW1S[4][KH];
  __shared__ float ebS[KH];
  __shared__ float eaS[EB][4];
  __shared__ __align__(16) unsigned int zB[EB * ZROW];
  __shared__ int esrcS[EB], edstS[EB];
  __shared__ __align__(16) unsigned short hF[QMFMA ? 2 : 1][64][8];

  const int f = *flag;
  const int tid = threadIdx.x;
  const int o = tid & 63;
  const int kq = tid >> 6;  // wave id 0..7
  const int n0 = blockIdx.x * NPG;

  // ---- stage h rows, eW1, eb1 ----
  for (int idx = tid; idx < NPG * IN; idx += 512) {
    int n = idx / IN, i = idx - n * IN;
    hA[n][i] = (HMODE == 1) ? ((const float*)h_in)[(n0 + n) * IN + i]
                            : ldf(h_in, (n0 + n) * IN + i, f);
  }
  for (int idx = tid; idx < 4 * KH; idx += 512)
    ((float*)eW1S)[idx] = ldf(eW1, idx, f);
  for (int idx = tid; idx < KH; idx += 512) ebS[idx] = ldf(eb1, idx, f);
  __syncthreads();

  {  // r2[n][o]: wave kq owns nodes kq*2, kq*2+1
    const int nb = kq * 2;
    float a0 = 0.f, a1 = 0.f;
    for (int i = 0; i < IN; i++) {
      float wv = ldf(eb2, i * 64 + o, f);
      a0 += hA[nb + 0][i] * wv;
      a1 += hA[nb + 1][i] * wv;
    }
    r2h[nb + 0][o] = (_Float16)a0;
    r2h[nb + 1][o] = (_Float16)a1;
  }
  if constexpr (QMFMA) {  // A-fragment staging (lane l: m=l&15, k=ks*32+quad*8+j)
    if (tid < 128) {
      int l = tid & 63, ks = tid >> 6;
#pragma unroll
      for (int j = 0; j < 8; j++)
        hF[ks][l][j] = f2bfbits(hA[l & 15][ks * 32 + (l >> 4) * 8 + j]);
    }
  }
  __syncthreads();

  v8s aF0 = {}, aF1 = {};
  if constexpr (QMFMA) {
    aF0 = *(const v8s*)&hF[0][o][0];
    aF1 = *(const v8s*)&hF[1][o][0];
  }

  const int estart = src_off[n0];
  const int ecount = src_off[n0 + NPG] - estart;

  for (int b = 0; b < ecount; b += EB) {
    const int bc = min(EB, ecount - b);
    __syncthreads();  // prev-batch readers done before meta overwrite
    if (tid < bc) {
      int eid = ebs[estart + b + tid];
      esrcS[tid] = ei[eid] - n0;
      edstS[tid] = ei[NE + eid];
#pragma unroll
      for (int i = 0; i < 4; i++) eaS[tid][i] = ldf(ea, eid * 4 + i, f);
    }
    __syncthreads();  // meta/eaS visible to all

    float msg[EB / 8];
#pragma unroll
    for (int j = 0; j < EB / 8; j++) msg[j] = 0.f;
    const int lo = (bc * kq) >> 3, hi = (bc * (kq + 1)) >> 3;

    for (int c = 0; c < NCH; c++) {
      // ---- step 1: compute Q-chunk into regs + z-chunk into regs ----
      v4f acc8[8];
      float accv[NPG * 2];
      if constexpr (QMFMA) {
#pragma unroll
        for (int nt = 0; nt < 8; nt++) {
          acc8[nt] = (v4f){0.f, 0.f, 0.f, 0.f};
          const int k2 = c * KC + kq * 2 + (nt >> 2);
          const int Fb = (k2 * 4 + (nt & 3)) * 2;
          v8s b0 = *(const v8s*)(W2s + (size_t)Fb * 512 + o * 8);
          v8s b1 = *(const v8s*)(W2s + (size_t)(Fb + 1) * 512 + o * 8);
          acc8[nt] =
              __builtin_amdgcn_mfma_f32_16x16x32_bf16(aF0, b0, acc8[nt], 0, 0, 0);
          acc8[nt] =
              __builtin_amdgcn_mfma_f32_16x16x32_bf16(aF1, b1, acc8[nt], 0, 0, 0);
        }
      } else {
        const int kg0 = c * KC + kq * 2;
        const int w2base = kg0 * (IN * 64) + o;
        float w0[IN], w1[IN];
#pragma unroll
        for (int j = 0; j < IN; j++) {
          w0[j] = ldf(W2, w2base + j * 64, f);
          w1[j] = ldf(W2, w2base + IN * 64 + j * 64, f);
        }
#pragma unroll
        for (int n = 0; n < NPG; n++) {
          float a0 = 0.f, a1 = 0.f;
#pragma unroll
          for (int j = 0; j < IN; j++) {
            float hv = hA[n][j];
            a0 += hv * w0[j];
            a1 += hv * w1[j];
          }
          accv[n * 2 + 0] = a0;
          accv[n * 2 + 1] = a1;
        }
      }
      // z for this chunk: thread -> (edge = tid&127, 4 k's per quarter)
      const int ze = tid & 127, kseg = tid >> 7;  // kseg 0..3
      float zv[4];
      if (ze < bc) {
#pragma unroll
        for (int jj = 0; jj < 4; jj++) {
          int k2 = c * KC + kseg * 4 + jj;
          float a = ebS[k2];
#pragma unroll
          for (int i = 0; i < 4; i++) a += eaS[ze][i] * eW1S[i][k2];
          zv[jj] = fmaxf(a, 0.f);
        }
      }
      __syncthreads();  // prev message stage done reading Qc/zB
      // ---- step 3: write Qc + zB as packed f16 pairs ----
      if constexpr (QMFMA) {
        const int quad = o >> 4;
#pragma unroll
        for (int nt = 0; nt < 4; nt++) {
          const int o2 = nt * 16 + (o & 15);
#pragma unroll
          for (int r = 0; r < 4; r++)
            Qc[(quad * 4 + r) * QNS + kq * 64 + o2] =
                pkh2(acc8[nt][r], acc8[nt + 4][r]);
        }
      } else {
#pragma unroll
        for (int n = 0; n < NPG; n++)
          Qc[n * QNS + kq * 64 + o] = pkh2(accv[n * 2 + 0], accv[n * 2 + 1]);
      }
      if (ze < bc) {
        uint2 p;
        p.x = pkh2(zv[0], zv[1]);
        p.y = pkh2(zv[2], zv[3]);
        *(uint2*)&zB[ze * ZROW + kseg * 2] = p;
      }
      __syncthreads();
      // ---- step 5: message accumulate via dot2 (contiguous edges) ----
      unsigned int q0 = 0, q1 = 0, q2 = 0, q3 = 0, q4 = 0, q5 = 0, q6 = 0,
                   q7 = 0;
      int sprev = -1;
#pragma unroll
      for (int j = 0; j < EB / 8; j++) {
        const int e = lo + j;
        if (e < hi) {
          const int s = esrcS[e];  // wave-uniform
          if (s != sprev) {
            const unsigned int* qp = &Qc[s * QNS + o];
            q0 = qp[0 * 64]; q1 = qp[1 * 64]; q2 = qp[2 * 64]; q3 = qp[3 * 64];
            q4 = qp[4 * 64]; q5 = qp[5 * 64]; q6 = qp[6 * 64]; q7 = qp[7 * 64];
            sprev = s;
          }
          const uint2 za = *(const uint2*)&zB[e * ZROW + 0];
          const uint2 zb2 = *(const uint2*)&zB[e * ZROW + 2];
          const uint2 zc = *(const uint2*)&zB[e * ZROW + 4];
          const uint2 zd = *(const uint2*)&zB[e * ZROW + 6];
          float m = msg[j];
          m = dot2a(za.x, q0, m);
          m = dot2a(za.y, q1, m);
          m = dot2a(zb2.x, q2, m);
          m = dot2a(zb2.y, q3, m);
          m = dot2a(zc.x, q4, m);
          m = dot2a(zc.y, q5, m);
          m = dot2a(zd.x, q6, m);
          m = dot2a(zd.y, q7, m);
          msg[j] = m;
        }
      }
    }  // chunks
    // ---- flush batch ----
#pragma unroll
    for (int j = 0; j < EB / 8; j++) {
      const int e = lo + j;
      if (e < hi)
        atomicAdd(&agg[(size_t)edstS[e] * 64 + o],
                  msg[j] + (float)r2h[esrcS[e]][o]);
    }
  }  // batches
}

// ---------------- wave-wide sum over 64 lanes ----------------
__device__ __forceinline__ float wave_sum(float v) {
#pragma unroll
  for (int m = 32; m >= 1; m >>= 1) v += __shfl_xor(v, m, 64);
  return v;
}

// ---------------- node update 1: h1 = LN(relu(agg/deg + x@root1 + bias1)) -
// 8 nodes per wave; root1 column hoisted to regs (R4: per-node tiny blocks
// were latency-bound at 4.4% VALUBusy).
__global__ __launch_bounds__(256, 4) void k_node1(
    const float* __restrict__ agg1, const int* __restrict__ deg_in,
    const void* __restrict__ x, const void* __restrict__ root1,
    const void* __restrict__ bias1, const void* __restrict__ g1,
    const void* __restrict__ b1, float* __restrict__ h1,
    const int* __restrict__ flag) {
  constexpr int NPW = 8;
  const int f = *flag;
  const int tid = threadIdx.x;
  const int o = tid & 63;
  const int w = tid >> 6;
  float r1c[4];
#pragma unroll
  for (int i = 0; i < 4; i++) r1c[i] = ldf(root1, i * 64 + o, f);
  const float bs = ldf(bias1, o, f);
  const float gv = ldf(g1, o, f);
  const float bv = ldf(b1, o, f);
  const int wid = blockIdx.x * 4 + w;
  const int nbeg = wid * NPW;
  const int nend = min(nbeg + NPW, NN);
  for (int n = nbeg; n < nend; n++) {
    float v = agg1[(size_t)n * 64 + o] / fmaxf((float)deg_in[n], 1.f) + bs;
#pragma unroll
    for (int i = 0; i < 4; i++) v += ldf(x, n * 4 + i, f) * r1c[i];
    v = fmaxf(v, 0.f);
    const float mu = wave_sum(v) * (1.f / 64.f);
    const float d = v - mu;
    const float var = wave_sum(d * d) * (1.f / 64.f);
    h1[(size_t)n * 64 + o] = d * rsqrtf(var + 1e-5f) * gv + bv;
  }
}

// ---------------- node update 2 + pooled accumulation ----------------
// 8 nodes per wave; root2 COLUMN in 64 VGPRs; h1 row via LDS broadcast;
// sorted-batch segment flush cuts psum atomics 1.28M -> ~180K.
__global__ __launch_bounds__(256, 4) void k_node2(
    const float* __restrict__ agg2, const int* __restrict__ deg_in,
    const float* __restrict__ h1, const void* __restrict__ root2,
    const void* __restrict__ bias2, const void* __restrict__ g2,
    const void* __restrict__ b2, const int* __restrict__ batch,
    float* __restrict__ psum, float* __restrict__ pcnt,
    const int* __restrict__ flag) {
  constexpr int NPW = 8;
  __shared__ float hS[4][64];
  const int f = *flag;
  const int tid = threadIdx.x;
  const int o = tid & 63;
  const int w = tid >> 6;
  float r2c[64];
#pragma unroll
  for (int i = 0; i < 64; i++) r2c[i] = ldf(root2, i * 64 + o, f);
  const float bs = ldf(bias2, o, f);
  const float gv = ldf(g2, o, f);
  const float bv = ldf(b2, o, f);
  const int wid = blockIdx.x * 4 + w;
  const int nbeg = wid * NPW;
  const int nend = min(nbeg + NPW, NN);
  float acc = 0.f;
  int curbi = -1, cnt = 0;
  for (int n = nbeg; n < nend; n++) {
    hS[w][o] = h1[(size_t)n * 64 + o];
    float v = agg2[(size_t)n * 64 + o] / fmaxf((float)deg_in[n], 1.f) + bs;
#pragma unroll
    for (int i = 0; i < 64; i++) v += hS[w][i] * r2c[i];
    v = fmaxf(v, 0.f);
    const float mu = wave_sum(v) * (1.f / 64.f);
    const float d = v - mu;
    const float var = wave_sum(d * d) * (1.f / 64.f);
    const float out = d * rsqrtf(var + 1e-5f) * gv + bv;
    const int bi = batch[n];
    if (bi != curbi) {
      if (curbi >= 0) {
        atomicAdd(&psum[curbi * 64 + o], acc);
        if (o == 0) atomicAdd(&pcnt[curbi], (float)cnt);
      }
      acc = 0.f;
      cnt = 0;
      curbi = bi;
    }
    acc += out;
    cnt++;
  }
  if (curbi >= 0) {
    atomicAdd(&psum[curbi * 64 + o], acc);
    if (o == 0) atomicAdd(&pcnt[curbi], (float)cnt);
  }
}

// ---------------- final mean + dtype-flagged output ----------------
__global__ __launch_bounds__(256) void k_out(const float* __restrict__ psum,
                                             const float* __restrict__ pcnt,
                                             void* __restrict__ out,
                                             const int* __restrict__ flag) {
  const int idx = blockIdx.x * 256 + threadIdx.x;  // 4096 total
  float v = psum[idx] / fmaxf(pcnt[idx >> 6], 1.f);
  if (*flag)
    ((bf16*)out)[idx] = __float2bfloat16(v);
  else
    ((float*)out)[idx] = v;
}

extern "C" void kernel_launch(void* const* d_in, const int* in_sizes, int n_in,
                              void* d_out, int out_size, void* d_ws,
                              size_t ws_size, hipStream_t stream) {
  (void)in_sizes; (void)n_in; (void)out_size; (void)ws_size;
  const void* x = d_in[0];
  const int* ei = (const int*)d_in[1];
  const void* ea = d_in[2];
  const int* batch = (const int*)d_in[3];
  const void* eW1_1 = d_in[4];
  const void* eb1_1 = d_in[5];
  const void* eW2_1 = d_in[6];
  const void* eb2_1 = d_in[7];
  const void* root1 = d_in[8];
  const void* bias1 = d_in[9];
  const void* g1 = d_in[10];
  const void* b1 = d_in[11];
  const void* eW1_2 = d_in[12];
  const void* eb1_2 = d_in[13];
  const void* eW2_2 = d_in[14];
  const void* eb2_2 = d_in[15];
  const void* root2 = d_in[16];
  const void* bias2 = d_in[17];
  const void* g2 = d_in[18];
  const void* b2 = d_in[19];

  char* w = (char*)d_ws;
  size_t off = 0;
  auto alloc = [&](size_t bytes) -> void* {
    void* p = w + off;
    off = (off + bytes + 255) & ~(size_t)255;
    return p;
  };
  float* agg1 = (float*)alloc((size_t)NN * 64 * 4);
  float* agg2 = (float*)alloc((size_t)NN * 64 * 4);
  float* psum = (float*)alloc((size_t)NGR * 64 * 4);
  float* pcnt = (float*)alloc((size_t)NGR * 4);
  int* deg_src = (int*)alloc((size_t)NN * 4);
  int* deg_in = (int*)alloc((size_t)NN * 4);
  const size_t zero_bytes = off;  // everything above must start at 0
  int* src_off = (int*)alloc((size_t)(NN + 1) * 4);
  int* cur = (int*)alloc((size_t)NN * 4);
  int* ebs = (int*)alloc((size_t)NE * 4);
  int* flag = (int*)alloc(256);
  float* h1 = (float*)alloc((size_t)NN * 64 * 4);
  unsigned short* W2s = (unsigned short*)alloc((size_t)128 * 8 * 64 * 8 * 2);

  hipMemsetAsync(d_ws, 0, zero_bytes, stream);

  k_detect<<<1, 64, 0, stream>>>((const unsigned short*)x, flag);
  k_deg<<<(NE + 255) / 256, 256, 0, stream>>>(ei, deg_src, deg_in);
  k_scan<<<1, 256, 0, stream>>>(deg_src, src_off, cur);
  k_scatter<<<(NE + 255) / 256, 256, 0, stream>>>(ei, cur, ebs);
  k_shuffle<128, 64><<<256, 256, 0, stream>>>(eW2_2, W2s, flag);
  k_fused2<4, 64, 0, 0><<<NN / 16, 512, 0, stream>>>(
      x, eW1_1, eb1_1, eW2_1, W2s, eb2_1, ea, ei, src_off, ebs, agg1, flag);
  k_node1<<<(NN + 8 * 4 - 1) / (8 * 4), 256, 0, stream>>>(
      agg1, deg_in, x, root1, bias1, g1, b1, h1, flag);
  k_fused2<64, 128, 1, 1><<<NN / 16, 512, 0, stream>>>(
      h1, eW1_2, eb1_2, eW2_2, W2s, eb2_2, ea, ei, src_off, ebs, agg2, flag);
  k_node2<<<(NN + 8 * 4 - 1) / (8 * 4), 256, 0, stream>>>(
      agg2, deg_in, h1, root2, bias2, g2, b2, batch, psum, pcnt, flag);
  k_out<<<(NGR * 64) / 256, 256, 0, stream>>>(psum, pcnt, d_out, flag);
}